// Round 1
// 899.114 us; speedup vs baseline: 1.0134x; 1.0134x over previous
//
#include <hip/hip_runtime.h>
#include <hip/hip_bf16.h>

// Problem constants
#define B_ROWS 16384
#define XC     10242      // 1 rate + 25 genre + 2186 director + 8030 actor
#define NGENRE 25
#define NDIR   2186
#define NACT   8030
#define EMB    32
#define KT_TOTAL 321      // ceil(10242/32) k-tiles of 32
#define OUTC   128
#define NCOLS  112        // slab cols: 96 emb + 3 counts + pad
#define PART_STRIDE ((size_t)B_ROWS * NCOLS)
#define WFRAG_BYTES ((size_t)KT_TOTAL * 4 * 64 * 16)   // 1.31 MB

typedef short bf16x8 __attribute__((ext_vector_type(8)));
typedef float f32x4  __attribute__((ext_vector_type(4)));
typedef float f32x4a __attribute__((ext_vector_type(4), aligned(4)));
typedef int   i32x4a __attribute__((ext_vector_type(4), aligned(4)));

// ===========================================================================
// Prep: pre-convert block-diagonal W into bf16 B-fragments, fragment-linear.
// B-frag: lane l holds B[k=kt*32+(l>>4)*8+j][n=l&15]. 4 slots/kt; boundary
// tiles (0, 69) use all 4 pre-masked; interior tiles use slots 0,1.
// R11: interior tiles load their 8 consecutive floats as 2x float4.
// ===========================================================================
__global__ void prep_wfrag(const float* __restrict__ wg,
                           const float* __restrict__ wd,
                           const float* __restrict__ wa,
                           uint4* __restrict__ Wfrag) {
  const int kt = blockIdx.x;
  const int s  = threadIdx.x >> 6;       // slot 0..3
  const int l  = threadIdx.x & 63;
  const int n  = l & 15;
  const int k0 = kt * 32 + ((l >> 4) << 3);

  float f[8];
  bool done = false;
  if (s < 2) {
    if (kt >= 1 && kt < 69) {            // interior director: k0..k0+7 all in-range
      const float* p = wd + (size_t)(s * 16 + n) * NDIR + (k0 - 26);
      f32x4a v0 = *reinterpret_cast<const f32x4a*>(p);
      f32x4a v1 = *reinterpret_cast<const f32x4a*>(p + 4);
      f[0]=v0[0]; f[1]=v0[1]; f[2]=v0[2]; f[3]=v0[3];
      f[4]=v1[0]; f[5]=v1[1]; f[6]=v1[2]; f[7]=v1[3];
      done = true;
    } else if (kt >= 70 && kt < 320) {   // interior actor
      const float* p = wa + (size_t)(s * 16 + n) * NACT + (k0 - 2212);
      f32x4a v0 = *reinterpret_cast<const f32x4a*>(p);
      f32x4a v1 = *reinterpret_cast<const f32x4a*>(p + 4);
      f[0]=v0[0]; f[1]=v0[1]; f[2]=v0[2]; f[3]=v0[3];
      f[4]=v1[0]; f[5]=v1[1]; f[6]=v1[2]; f[7]=v1[3];
      done = true;
    }
  }
  if (!done) {
#pragma unroll
    for (int j = 0; j < 8; ++j) {
      const int k = k0 + j;
      float v = 0.f;
      if (kt == 0) {
        if (s < 2) { if (k >= 1 && k < 26) v = wg[(s * 16 + n) * NGENRE + (k - 1)]; }
        else       { if (k >= 26)          v = wd[((s - 2) * 16 + n) * NDIR + (k - 26)]; }
      } else if (kt == 69) {
        if (s < 2) { if (k < 2212)  v = wd[(s * 16 + n) * NDIR + (k - 26)]; }
        else       { if (k >= 2212) v = wa[((s - 2) * 16 + n) * NACT + (k - 2212)]; }
      } else if (kt == 320) {
        if (s < 2 && k < XC) v = wa[(s * 16 + n) * NACT + (k - 2212)];
      }
      // interior tiles with s>=2: stay 0
      f[j] = v;
    }
  }
  union { unsigned short u[8]; uint4 q; } cv;
#pragma unroll
  for (int j = 0; j < 8; ++j) {
    __hip_bfloat16 h = __float2bfloat16(f[j]);
    cv.u[j] = *reinterpret_cast<unsigned short*>(&h);
  }
  Wfrag[((size_t)kt * 4 + s) * 64 + l] = cv.q;
}

// ===========================================================================
// Main (R11): counted-vmcnt pipeline. Per group of 4 k-tiles:
//   [8 B-frag loads (group g)] -> [8 x-loads (group g+1)] -> [consume g]
// Every MFMA waits only on FIFO-older loads, so the next group's x-loads
// stay in flight across the whole consume phase (no vmcnt(0) drains except
// at the 3 boundary tiles' lazy slot-2/3 loads). Ping-pong x-register sets.
// A-frag: lane holds A[m=lane&15][k=(lane>>4)*8+j]; C/D row=(lane>>4)*4+j,
// col=lane&15. Pack: (x0 + (x1<<16)) * 0x3F80 (exact for x in {0,1}).
// ===========================================================================
template<int KS>
__global__ __launch_bounds__(256) void main_mm(const int* __restrict__ x,
                                               const uint4* __restrict__ Wfrag,
                                               float* __restrict__ part) {
  constexpr int PER = (((KT_TOTAL + KS - 1) / KS) + 3) & ~3;   // multiple of 4
  const int t    = threadIdx.x;
  const int rb   = blockIdx.x & 255;
  const int ks   = blockIdx.x >> 8;
  const int ktA  = ks * PER;
  const int ktB  = (ktA + PER < KT_TOTAL) ? ktA + PER : KT_TOTAL;
  const int lane = t & 63;
  const int w    = t >> 6;
  const int lo   = lane & 15, hi = lane >> 4;
  const int* xrow = x + (size_t)(rb * 64 + w * 16 + lo) * XC;

  f32x4 accG0 = {0,0,0,0}, accG1 = {0,0,0,0};
  f32x4 accD0 = {0,0,0,0}, accD1 = {0,0,0,0};
  f32x4 accA0 = {0,0,0,0}, accA1 = {0,0,0,0};
  f32x4 accI  = {0,0,0,0};

  auto load_x8 = [&](int kt, int* dst) {
    int k0 = kt * 32 + hi * 8;
    if (kt < 320) {          // wave-uniform in-bounds: k0+7 <= 10239 < XC
      i32x4a a = *reinterpret_cast<const i32x4a*>(xrow + k0);
      i32x4a b = *reinterpret_cast<const i32x4a*>(xrow + k0 + 4);
      dst[0]=a[0]; dst[1]=a[1]; dst[2]=a[2]; dst[3]=a[3];
      dst[4]=b[0]; dst[5]=b[1]; dst[6]=b[2]; dst[7]=b[3];
    } else {                 // tail tile: per-lane masked scalar loads
#pragma unroll
      for (int j = 0; j < 8; ++j) dst[j] = (k0 + j < XC) ? xrow[k0 + j] : 0;
    }
  };
  auto packa = [&](const int* cx) -> bf16x8 {
    union { unsigned int w4[4]; bf16x8 v; } af;
#pragma unroll
    for (int i = 0; i < 4; ++i)
      af.w4[i] = ((unsigned)cx[2*i] + ((unsigned)cx[2*i+1] << 16)) * 0x3F80u;
    return af.v;
  };
  auto bload = [&](int kt, int s) -> bf16x8 {
    union { uint4 q; bf16x8 v; } c;
    c.q = Wfrag[((size_t)kt * 4 + s) * 64 + lane];
    return c.v;
  };
  auto mkconst = [&](bool on) -> bf16x8 {
    union { unsigned int w4[4]; bf16x8 v; } c;
    unsigned int u = on ? 0x3F803F80u : 0u;
    c.w4[0]=u; c.w4[1]=u; c.w4[2]=u; c.w4[3]=u;
    return c.v;
  };
  const bf16x8 ivD = mkconst(lo == 1);
  const bf16x8 ivA = mkconst(lo == 2);

  // Consume one k-tile. b0/b1 are the prefetched slot-0/1 B-frags; only the
  // 3 boundary tiles do lazy slot-2/3 loads (rare vmcnt drains).
  auto do_mfma = [&](int kt, bf16x8 a, bf16x8 b0, bf16x8 b1) {
    const int kb = kt * 32 + hi * 8;
    if (kt == 0) {
      accG0 = __builtin_amdgcn_mfma_f32_16x16x32_bf16(a, b0, accG0, 0,0,0);
      accG1 = __builtin_amdgcn_mfma_f32_16x16x32_bf16(a, b1, accG1, 0,0,0);
      accD0 = __builtin_amdgcn_mfma_f32_16x16x32_bf16(a, bload(0,2), accD0, 0,0,0);
      accD1 = __builtin_amdgcn_mfma_f32_16x16x32_bf16(a, bload(0,3), accD1, 0,0,0);
      union { unsigned short u[8]; bf16x8 v; } iv;
#pragma unroll
      for (int j = 0; j < 8; ++j) {
        int k = kb + j;
        bool on = (lo == 0) ? (k >= 1 && k < 26) : (lo == 1) ? (k >= 26) : false;
        iv.u[j] = on ? (unsigned short)0x3F80 : (unsigned short)0;
      }
      accI = __builtin_amdgcn_mfma_f32_16x16x32_bf16(a, iv.v, accI, 0,0,0);
    } else if (kt < 69) {
      accD0 = __builtin_amdgcn_mfma_f32_16x16x32_bf16(a, b0, accD0, 0,0,0);
      accD1 = __builtin_amdgcn_mfma_f32_16x16x32_bf16(a, b1, accD1, 0,0,0);
      accI  = __builtin_amdgcn_mfma_f32_16x16x32_bf16(a, ivD, accI, 0,0,0);
    } else if (kt == 69) {
      accD0 = __builtin_amdgcn_mfma_f32_16x16x32_bf16(a, b0, accD0, 0,0,0);
      accD1 = __builtin_amdgcn_mfma_f32_16x16x32_bf16(a, b1, accD1, 0,0,0);
      accA0 = __builtin_amdgcn_mfma_f32_16x16x32_bf16(a, bload(69,2), accA0, 0,0,0);
      accA1 = __builtin_amdgcn_mfma_f32_16x16x32_bf16(a, bload(69,3), accA1, 0,0,0);
      union { unsigned short u[8]; bf16x8 v; } iv;
#pragma unroll
      for (int j = 0; j < 8; ++j) {
        int k = kb + j;
        bool on = (lo == 1) ? (k < 2212) : (lo == 2) ? (k >= 2212) : false;
        iv.u[j] = on ? (unsigned short)0x3F80 : (unsigned short)0;
      }
      accI = __builtin_amdgcn_mfma_f32_16x16x32_bf16(a, iv.v, accI, 0,0,0);
    } else if (kt < 320) {
      accA0 = __builtin_amdgcn_mfma_f32_16x16x32_bf16(a, b0, accA0, 0,0,0);
      accA1 = __builtin_amdgcn_mfma_f32_16x16x32_bf16(a, b1, accA1, 0,0,0);
      accI  = __builtin_amdgcn_mfma_f32_16x16x32_bf16(a, ivA, accI, 0,0,0);
    } else {
      accA0 = __builtin_amdgcn_mfma_f32_16x16x32_bf16(a, b0, accA0, 0,0,0);
      accA1 = __builtin_amdgcn_mfma_f32_16x16x32_bf16(a, b1, accA1, 0,0,0);
      union { unsigned short u[8]; bf16x8 v; } iv;
#pragma unroll
      for (int j = 0; j < 8; ++j) {
        int k = kb + j;
        iv.u[j] = (lo == 2 && k < XC) ? (unsigned short)0x3F80 : (unsigned short)0;
      }
      accI = __builtin_amdgcn_mfma_f32_16x16x32_bf16(a, iv.v, accI, 0,0,0);
    }
  };

  int xA0[8], xA1[8], xA2[8], xA3[8];
  int xB0[8], xB1[8], xB2[8], xB3[8];

  auto load_group = [&](int g, int* d0, int* d1, int* d2, int* d3) {
    if (g     < ktB) load_x8(g,     d0);
    if (g + 1 < ktB) load_x8(g + 1, d1);
    if (g + 2 < ktB) load_x8(g + 2, d2);
    if (g + 3 < ktB) load_x8(g + 3, d3);
  };

  // Consume group g from s-buffers while prefetching group g+4 into d-buffers.
  // VMEM issue order: [bloads(g) x8] -> [xloads(g+4) x8] -> MFMAs. All waits
  // inside the consume phase are counted (leave the g+4 x-loads in flight).
  auto run_group = [&](int g,
                       const int* s0, const int* s1, const int* s2, const int* s3,
                       int* d0, int* d1, int* d2, int* d3) {
    bf16x8 b00 = bload(g, 0), b01 = bload(g, 1);
    bf16x8 b10, b11, b20, b21, b30, b31;
    if (g + 1 < ktB) { b10 = bload(g + 1, 0); b11 = bload(g + 1, 1); }
    if (g + 2 < ktB) { b20 = bload(g + 2, 0); b21 = bload(g + 2, 1); }
    if (g + 3 < ktB) { b30 = bload(g + 3, 0); b31 = bload(g + 3, 1); }
    load_group(g + 4, d0, d1, d2, d3);
    do_mfma(g, packa(s0), b00, b01);
    if (g + 1 < ktB) do_mfma(g + 1, packa(s1), b10, b11);
    if (g + 2 < ktB) do_mfma(g + 2, packa(s2), b20, b21);
    if (g + 3 < ktB) do_mfma(g + 3, packa(s3), b30, b31);
  };

  load_group(ktA, xA0, xA1, xA2, xA3);
  for (int g = ktA; g < ktB; g += 8) {
    run_group(g,     xA0, xA1, xA2, xA3, xB0, xB1, xB2, xB3);
    if (g + 4 < ktB)
      run_group(g + 4, xB0, xB1, xB2, xB3, xA0, xA1, xA2, xA3);
  }

  float* slab = part + (size_t)ks * PART_STRIDE;
  const int rbase = rb * 64 + w * 16 + hi * 4;
#pragma unroll
  for (int j = 0; j < 4; ++j) {
    size_t ro = (size_t)(rbase + j) * NCOLS;
    slab[ro +  0 + lo] = accG0[j];
    slab[ro + 16 + lo] = accG1[j];
    slab[ro + 32 + lo] = accD0[j];
    slab[ro + 48 + lo] = accD1[j];
    slab[ro + 64 + lo] = accA0[j];
    slab[ro + 80 + lo] = accA1[j];
    if (lo < 3) slab[ro + 96 + lo] = accI[j];
  }
}

// ===========================================================================
// Reduce + epilogue (unchanged): one row per 128-thread block, slab reads
// as float4 accumulated in registers, spread to the 96 division lanes via
// LDS. Rate max-norm path via shfl reduce.
// ===========================================================================
__global__ __launch_bounds__(128) void reduce_k(const int* __restrict__ x,
                                                const float* __restrict__ rate,
                                                const float* __restrict__ part,
                                                int ksplit,
                                                float* __restrict__ out) {
  __shared__ float srow[112];
  const int r = blockIdx.x;
  const int c = threadIdx.x;

  if (c < 28) {                       // 28 float4 = 112 floats (96+3+pad)
    f32x4 acc = {0.f, 0.f, 0.f, 0.f};
    for (int ks = 0; ks < ksplit; ++ks) {
      const float* p = part + (size_t)ks * PART_STRIDE + (size_t)r * NCOLS + c * 4;
      f32x4a v = *reinterpret_cast<const f32x4a*>(p);
      acc[0] += v[0]; acc[1] += v[1]; acc[2] += v[2]; acc[3] += v[3];
    }
    srow[c * 4 + 0] = acc[0];
    srow[c * 4 + 1] = acc[1];
    srow[c * 4 + 2] = acc[2];
    srow[c * 4 + 3] = acc[3];
  }
  __syncthreads();

  float res;
  if (c < EMB) {
    int idx = x[(size_t)r * XC];
    float v = rate[idx * EMB + c];
    float s2 = v * v;
    s2 += __shfl_xor(s2, 1, 32);
    s2 += __shfl_xor(s2, 2, 32);
    s2 += __shfl_xor(s2, 4, 32);
    s2 += __shfl_xor(s2, 8, 32);
    s2 += __shfl_xor(s2, 16, 32);
    float norm = sqrtf(s2);
    float scale = (norm > 1.0f) ? (1.0f / (norm + 1e-7f)) : 1.0f;
    res = v * scale;
  } else {
    int cc = c - EMB;                  // 0..95
    res = srow[cc] / srow[96 + (cc >> 5)];
  }
  out[(size_t)r * OUTC + c] = res;
}

// ---------------------------------------------------------------------------
extern "C" void kernel_launch(void* const* d_in, const int* in_sizes, int n_in,
                              void* d_out, int out_size, void* d_ws, size_t ws_size,
                              hipStream_t stream) {
  (void)in_sizes; (void)n_in; (void)out_size;
  const int*   x    = (const int*)d_in[0];
  const float* rate = (const float*)d_in[1];
  const float* wg   = (const float*)d_in[2];
  const float* wd   = (const float*)d_in[3];
  const float* wa   = (const float*)d_in[4];
  float* out  = (float*)d_out;
  float* part = (float*)d_ws;

  const size_t slab_bytes = PART_STRIDE * sizeof(float);   // 7.34 MB
  int KS;
  if      (ws_size >= 4 * slab_bytes + WFRAG_BYTES) KS = 4;
  else if (ws_size >= 2 * slab_bytes + WFRAG_BYTES) KS = 2;
  else                                              KS = 1;
  uint4* Wfrag = (uint4*)((char*)d_ws + (size_t)KS * slab_bytes);

  prep_wfrag<<<KT_TOTAL, 256, 0, stream>>>(wg, wd, wa, Wfrag);
  switch (KS) {
    case 4: main_mm<4><<<4 * 256, 256, 0, stream>>>(x, Wfrag, part); break;
    case 2: main_mm<2><<<2 * 256, 256, 0, stream>>>(x, Wfrag, part); break;
    default: main_mm<1><<<1 * 256, 256, 0, stream>>>(x, Wfrag, part); break;
  }
  reduce_k<<<B_ROWS, 128, 0, stream>>>(x, rate, part, KS, out);
}